// Round 7
// baseline (1234.364 us; speedup 1.0000x reference)
//
#include <hip/hip_runtime.h>
#include <float.h>
#include <math.h>

#define DIM 512
#define EPSN 1e-12f

typedef _Float16 f16x8 __attribute__((ext_vector_type(8)));
typedef float f32x4 __attribute__((ext_vector_type(4)));

// ---------------- wave (64-lane) sum ----------------
__device__ inline float wave_sum(float v) {
#pragma unroll
  for (int o = 32; o > 0; o >>= 1) v += __shfl_xor(v, o, 64);
  return v;
}

// one wave per emb row: eepair[j] = { sum(embn^2), 1/max(||emb_j||,eps) }
__global__ __launch_bounds__(256) void emb_norm_kernel(
    const float* __restrict__ emb, float2* __restrict__ eepair) {
  int row = blockIdx.x * 4 + (threadIdx.x >> 6);
  int lane = threadIdx.x & 63;
  const float* p = emb + (size_t)row * DIM;
  float x[8];
  float ss = 0.f;
#pragma unroll
  for (int i = 0; i < 8; ++i) { x[i] = p[i * 64 + lane]; ss += x[i] * x[i]; }
  ss = wave_sum(ss);
  float d = fmaxf(sqrtf(ss), EPSN);
  float ee = 0.f;
#pragma unroll
  for (int i = 0; i < 8; ++i) { float y = x[i] / d; ee += y * y; }
  ee = wave_sum(ee);
  if (lane == 0) eepair[row] = make_float2(ee, 1.0f / d);
}

// one wave per z row: zinv[n] = 1/max(||z_n||,eps)  (used by finalize only)
__global__ __launch_bounds__(256) void z_norm_kernel(
    const float* __restrict__ z, float* __restrict__ zinv) {
  int row = blockIdx.x * 4 + (threadIdx.x >> 6);
  int lane = threadIdx.x & 63;
  const float* p = z + (size_t)row * DIM;
  float ss = 0.f;
#pragma unroll
  for (int i = 0; i < 8; ++i) { float v = p[i * 64 + lane]; ss += v * v; }
  ss = wave_sum(ss);
  if (lane == 0) zinv[row] = 1.0f / fmaxf(sqrtf(ss), EPSN);
}

// ---------------- emb -> swizzled hi/lo fp16 of (embn * 1024) --------------
// swz layout: chunk c = (tile16 * 16 + kc) * 2 + half, each chunk = 64 lanes
// x 8 f16 (1 KB); element (lane = quad*16+col, j) = embn[tile16*16+col]
// [kc*32 + quad*8 + j] * 1024, split hi/lo. Normalized codebook (x1024 keeps
// the lo half out of fp16 subnormals) makes argmin(dist) == argmax(dot):
// ||zn||^2 is per-row constant and ||embn||^2 = 1 +- 2^-23, perturbation
// ~100x below the fp16 hi/lo dot error that already passes.
__global__ __launch_bounds__(256) void emb_split_kernel(
    const float* __restrict__ emb, const float2* __restrict__ eepair,
    _Float16* __restrict__ swz) {
  int g = blockIdx.x * 256 + threadIdx.x;  // = t*1024 + kc*64 + lane
  int lane = g & 63;
  int kc = (g >> 6) & 15;
  int t = g >> 10;
  int code = t * 16 + (lane & 15);
  int k0 = kc * 32 + (lane >> 4) * 8;
  float sc = 1024.0f * eepair[code].y;
  const float* src = emb + (size_t)code * DIM + k0;
  float4 a = *(const float4*)src;
  float4 b = *(const float4*)(src + 4);
  float v[8] = {a.x, a.y, a.z, a.w, b.x, b.y, b.z, b.w};
  f16x8 h, l;
#pragma unroll
  for (int k = 0; k < 8; ++k) {
    float vs = v[k] * sc;
    _Float16 hh = (_Float16)vs;
    h[k] = hh;
    l[k] = (_Float16)(vs - (float)hh);
  }
  size_t cbase = ((size_t)(t * 16 + kc) * 2) * 512;  // f16 units
  *(f16x8*)&swz[cbase + lane * 8] = h;
  *(f16x8*)&swz[cbase + 512 + lane * 8] = l;
}

// ---------------- MFMA dot + per-partition argmax ----------------
// r5 post-mortem: cycle model validated against counters -- per CU per
// tile-pair: matrix pipe 3725 cyc, LDS reads 576KB/79B/cyc = 7290 cyc,
// measured 7270. The kernel sits at 99% of the LDS-read roofline (bank
// conflicts 0, pattern already optimal): every wave re-reads the whole B
// tile per 16 rows it owns. Fix = 2x rows per B read: 32 rows/wave.
//
// That needs A hi/lo = 256 VGPR, which is exactly what spilled in r0-r4 at
// 2 waves/SIMD (256-VGPR cap). Resolution: 4-wave blocks at 1 wave/SIMD --
// __launch_bounds__(256,1) gives the 512-VGPR budget (no spill through
// ~450, m08/m24). Total ~380 VGPR. Per tile: LDS = 4x32+32 = 160KB (~1950
// cyc) vs matrix = 4w x 96 MFMA x 19.4/4 = 1862 cyc -> matrix-bound.
// Everything else is the r5-verified skeleton: plain __syncthreads() only
// (no inline-asm sync -- r4's nondeterminism), reg-staged B (per-lane
// dwordx4 -> regs -> ds_write), depth-2 prefetch issued before compute so
// the barrier's implicit vmcnt(0) finds loads complete, 2x32KB ping-pong,
// partition (blockIdx&7) == XCD under round-robin so the 2.1MB codebook
// slice stays L2-resident.
#define MFMA16(A, B, C) __builtin_amdgcn_mfma_f32_16x16x32_f16(A, B, C, 0, 0, 0)

__global__ __launch_bounds__(256, 1) void dist_argmin_kernel(
    const float* __restrict__ z, const _Float16* __restrict__ swz,
    int ne, int nrows, float* __restrict__ pscore, int* __restrict__ pidx) {
  __shared__ __attribute__((aligned(16))) _Float16 Bb[2][16384];  // 2 x 32 KB

  const int tid = threadIdx.x;
  const int wave = tid >> 6;   // 0..3
  const int lane = tid & 63;
  const int col = lane & 15;
  const int quad = lane >> 4;
  const int part = blockIdx.x & 7;          // codebook partition
  const int r0 = (blockIdx.x >> 3) * 128 + wave * 32;
  const int ntl = ne >> 7;                  // 64 16-code tiles per partition
  const int tbase = part * ntl;             // global tile base

  float best[2][4] = {{-FLT_MAX, -FLT_MAX, -FLT_MAX, -FLT_MAX},
                      {-FLT_MAX, -FLT_MAX, -FLT_MAX, -FLT_MAX}};
  int bidx[2][4] = {{0, 0, 0, 0}, {0, 0, 0, 0}};

  // ---- staging: wave covers 8 x 1KB chunks (32KB tile / 4 waves) ----
  f16x8 R0[8], R1[8];
  auto load_tile = [&](int t, f16x8* R) {
    const _Float16* gb =
        swz + (size_t)(tbase + t) * 16384 + (wave * 8) * 512 + lane * 8;
#pragma unroll
    for (int i = 0; i < 8; ++i) R[i] = *(const f16x8*)(gb + i * 512);
  };
  auto write_tile = [&](int buf, const f16x8* R) {
    _Float16* lb = &Bb[buf][(wave * 8) * 512 + lane * 8];
#pragma unroll
    for (int i = 0; i < 8; ++i) *(f16x8*)(lb + i * 512) = R[i];
  };

  // issue tiles 0,1 loads first; they complete under the A-fragment build
  load_tile(0, R0);
  load_tile(1, R1);

  // persistent A fragments (hi/lo) for this wave's 32 rows, from RAW z
  // (argmax of dot is invariant to the positive per-row scale zinv).
  // 2 x (16+16) f16x8 = 256 VGPRs -- deliberate: 1 wave/SIMD, 512-VGPR
  // budget, no spill (the r0-r4 bug is the 2-wave/SIMD 256 cap).
  f16x8 Ah[2][16], Al[2][16];
#pragma unroll
  for (int rb = 0; rb < 2; ++rb) {
    const float* zp = z + (size_t)(r0 + rb * 16 + col) * DIM + quad * 8;
#pragma unroll
    for (int kc = 0; kc < 16; ++kc) {
      float4 a = *(const float4*)(zp + kc * 32);
      float4 b = *(const float4*)(zp + kc * 32 + 4);
      float v[8] = {a.x, a.y, a.z, a.w, b.x, b.y, b.z, b.w};
#pragma unroll
      for (int k = 0; k < 8; ++k) {
        _Float16 h = (_Float16)v[k];
        Ah[rb][kc][k] = h;
        Al[rb][kc][k] = (_Float16)(v[k] - (float)h);
      }
    }
  }

  auto compute_tile = [&](int t, int buf) {
    f32x4 acc[2][3];
#pragma unroll
    for (int rb = 0; rb < 2; ++rb)
#pragma unroll
      for (int a = 0; a < 3; ++a) acc[rb][a] = (f32x4){0.f, 0.f, 0.f, 0.f};

    const _Float16* bp = &Bb[buf][lane * 8];
    __builtin_amdgcn_s_setprio(1);
#pragma unroll
    for (int kc = 0; kc < 16; ++kc) {
      f16x8 bh = *(const f16x8*)(bp + (kc * 2) * 512);
      f16x8 bl = *(const f16x8*)(bp + (kc * 2 + 1) * 512);
      acc[0][0] = MFMA16(Ah[0][kc], bh, acc[0][0]);
      acc[1][0] = MFMA16(Ah[1][kc], bh, acc[1][0]);
      acc[0][1] = MFMA16(Al[0][kc], bh, acc[0][1]);
      acc[1][1] = MFMA16(Al[1][kc], bh, acc[1][1]);
      acc[0][2] = MFMA16(Ah[0][kc], bl, acc[0][2]);
      acc[1][2] = MFMA16(Ah[1][kc], bl, acc[1][2]);
    }
    __builtin_amdgcn_s_setprio(0);

    // epilogue: pure argmax of the dot. Tiles ascend in j within the
    // partition, so strict '>' keeps the first (lowest) index on ties.
    int j = (tbase + t) * 16 + col;
#pragma unroll
    for (int rb = 0; rb < 2; ++rb)
#pragma unroll
      for (int i = 0; i < 4; ++i) {
        float d = acc[rb][0][i] + acc[rb][1][i] + acc[rb][2][i];
        if (d > best[rb][i]) { best[rb][i] = d; bidx[rb][i] = j; }
      }
  };

  // prologue: buf0 <- tile0 (compiler inserts the counted vmcnt for R0)
  write_tile(0, R0);
  __syncthreads();

  // 2-unrolled ping-pong, one __syncthreads per tile (r5-verified skeleton).
  // Buffer safety: the write to buf X is after compute(buf X)'s reads
  // drained at the previous barrier, and before the barrier that precedes
  // the next compute(buf X). Register safety: load overwrites R[x] only
  // after R[x]'s ds_writes drained at a previous barrier.
  for (int t = 0; t < ntl; t += 2) {          // ntl = 64, even
    if (t + 2 < ntl) load_tile(t + 2, R0);    // hides under compute
    compute_tile(t, 0);
    write_tile(1, R1);                        // tile t+1 -> buf1
    __syncthreads();

    if (t + 3 < ntl) load_tile(t + 3, R1);
    compute_tile(t + 1, 1);
    if (t + 2 < ntl) write_tile(0, R0);       // tile t+2 -> buf0
    __syncthreads();
  }

  // merge across the 16 columns within each quad (xor 1,2,4,8 stays in quad)
#pragma unroll
  for (int rb = 0; rb < 2; ++rb)
#pragma unroll
    for (int i = 0; i < 4; ++i) {
      float bs = best[rb][i];
      int bj = bidx[rb][i];
#pragma unroll
      for (int offm = 1; offm < 16; offm <<= 1) {
        float os = __shfl_xor(bs, offm, 64);
        int oi = __shfl_xor(bj, offm, 64);
        if (os > bs || (os == bs && oi < bj)) { bs = os; bj = oi; }
      }
      if (col == 0) {
        int row = r0 + rb * 16 + quad * 4 + i;
        pscore[(size_t)part * nrows + row] = bs;
        pidx[(size_t)part * nrows + row] = bj;
      }
    }
}

// fold the 8 per-partition partials per row; ascending p + strict '>'
// preserves global first-index semantics (partitions hold ascending ranges)
__global__ __launch_bounds__(256) void merge_kernel(
    const float* __restrict__ pscore, const int* __restrict__ pidx,
    int nrows, int* __restrict__ idxw, float* __restrict__ counts,
    float* __restrict__ out_idx) {
  int row = blockIdx.x * 256 + threadIdx.x;
  float bs = pscore[row];
  int bj = pidx[row];
#pragma unroll
  for (int p = 1; p < 8; ++p) {
    float s = pscore[(size_t)p * nrows + row];
    int j2 = pidx[(size_t)p * nrows + row];
    if (s > bs || (s == bs && j2 < bj)) { bs = s; bj = j2; }
  }
  idxw[row] = bj;
  out_idx[row] = (float)bj;
  atomicAdd(&counts[bj], 1.0f);
}

// one wave per row: z_q_st = normalize(q); per-block loss partial
__global__ __launch_bounds__(256) void finalize_rows_kernel(
    const float* __restrict__ z, const float* __restrict__ emb,
    const int* __restrict__ idxw, const float* __restrict__ zinv,
    float* __restrict__ out_zq, float* __restrict__ lpart) {
  __shared__ float red[4];
  int row = blockIdx.x * 4 + (threadIdx.x >> 6);
  int lane = threadIdx.x & 63;
  int j = idxw[row];
  const float* zp = z + (size_t)row * DIM;
  const float* qp = emb + (size_t)j * DIM;
  float zl[8], ql[8], tl[8];
  float st = 0.f, sq = 0.f;
#pragma unroll
  for (int i = 0; i < 8; ++i) {
    int k = i * 64 + lane;
    float zv = zp[k], qv = qp[k];
    float t = zv + (qv - zv);  // straight-through, literal arithmetic
    zl[i] = zv; ql[i] = qv; tl[i] = t;
    st += t * t;
    sq += qv * qv;
  }
  st = wave_sum(st);
  sq = wave_sum(sq);
  float dt = fmaxf(sqrtf(st), EPSN);
  float dq = fmaxf(sqrtf(sq), EPSN);
  float zi = zinv[row];
  float lp = 0.f;
#pragma unroll
  for (int i = 0; i < 8; ++i) {
    int k = i * 64 + lane;
    out_zq[(size_t)row * DIM + k] = tl[i] / dt;
    float e = ql[i] / dq - zl[i] * zi;
    lp += e * e;
  }
  lp = wave_sum(lp);
  if (lane == 0) red[threadIdx.x >> 6] = lp;
  __syncthreads();
  if (threadIdx.x == 0) lpart[blockIdx.x] = red[0] + red[1] + red[2] + red[3];
}

// single block: loss scalar (sum of block partials) + perplexity from counts
__global__ __launch_bounds__(256) void scalars_kernel(
    const float* __restrict__ counts, const float* __restrict__ lpart,
    int ne, int nblk, float inv_n, float inv_total,
    float* __restrict__ out_loss, float* __restrict__ out_perp) {
  __shared__ float red[8];
  int tid = threadIdx.x;
  float s = 0.f;
  for (int jj = tid; jj < ne; jj += 256) {
    float p = counts[jj] * inv_n;
    s += p * logf(p + 1e-10f);
  }
  float l = 0.f;
  for (int jj = tid; jj < nblk; jj += 256) l += lpart[jj];
  s = wave_sum(s);
  l = wave_sum(l);
  if ((tid & 63) == 0) { red[tid >> 6] = s; red[4 + (tid >> 6)] = l; }
  __syncthreads();
  if (tid == 0) {
    float t = red[0] + red[1] + red[2] + red[3];
    float lt = red[4] + red[5] + red[6] + red[7];
    *out_perp = expf(-t);
    *out_loss = 1.25f * lt * inv_total;  // (1+BETA)*mean, sg() identity fwd
  }
}

extern "C" void kernel_launch(void* const* d_in, const int* in_sizes, int n_in,
                              void* d_out, int out_size, void* d_ws, size_t ws_size,
                              hipStream_t stream) {
  const float* z = (const float*)d_in[0];
  const float* emb = (const float*)d_in[1];
  float* out = (float*)d_out;
  float* ws = (float*)d_ws;

  const int nrows = in_sizes[0] / DIM;  // 32768
  const int ne = in_sizes[1] / DIM;     // 8192
  const int nfin = nrows / 4;           // finalize blocks

  // workspace layout (floats)
  float2* eepair = (float2*)ws;                  // ne float2
  float* zinv = ws + 2 * ne;                     // nrows
  int* idxw = (int*)(ws + 2 * ne + nrows);       // nrows
  float* counts = ws + 2 * ne + 2 * nrows;       // ne
  float* lpart = counts + ne;                    // nfin
  float* pscore = lpart + nfin;                  // 8 * nrows
  int* pidx = (int*)(pscore + 8 * (size_t)nrows);// 8 * nrows
  _Float16* swz = (_Float16*)(pidx + 8 * (size_t)nrows);  // ne*1024 f16

  float* out_zq = out + 1;
  float* out_idx = out + 1 + (size_t)nrows * DIM;
  float* out_perp = out + (size_t)out_size - 1;

  hipMemsetAsync(counts, 0, ne * sizeof(float), stream);
  emb_norm_kernel<<<ne / 4, 256, 0, stream>>>(emb, eepair);
  z_norm_kernel<<<nrows / 4, 256, 0, stream>>>(z, zinv);
  emb_split_kernel<<<ne * 64 / 256, 256, 0, stream>>>(emb, eepair, swz);
  dist_argmin_kernel<<<(nrows / 128) * 8, 256, 0, stream>>>(z, swz, ne, nrows,
                                                            pscore, pidx);
  merge_kernel<<<nrows / 256, 256, 0, stream>>>(pscore, pidx, nrows,
                                                idxw, counts, out_idx);
  finalize_rows_kernel<<<nfin, 256, 0, stream>>>(z, emb, idxw, zinv,
                                                 out_zq, lpart);
  scalars_kernel<<<1, 256, 0, stream>>>(counts, lpart, ne, nfin,
                                        1.0f / (float)nrows,
                                        1.0f / (float)((size_t)nrows * DIM),
                                        out, out_perp);
}

// Round 8
// 1038.301 us; speedup vs baseline: 1.1888x; 1.1888x over previous
//
#include <hip/hip_runtime.h>
#include <float.h>
#include <math.h>

#define DIM 512
#define EPSN 1e-12f

typedef _Float16 f16x8 __attribute__((ext_vector_type(8)));
typedef float f32x4 __attribute__((ext_vector_type(4)));

// ---------------- wave (64-lane) sum ----------------
__device__ inline float wave_sum(float v) {
#pragma unroll
  for (int o = 32; o > 0; o >>= 1) v += __shfl_xor(v, o, 64);
  return v;
}

// one wave per emb row: eepair[j] = { sum(embn^2), 1/max(||emb_j||,eps) }
__global__ __launch_bounds__(256) void emb_norm_kernel(
    const float* __restrict__ emb, float2* __restrict__ eepair) {
  int row = blockIdx.x * 4 + (threadIdx.x >> 6);
  int lane = threadIdx.x & 63;
  const float* p = emb + (size_t)row * DIM;
  float x[8];
  float ss = 0.f;
#pragma unroll
  for (int i = 0; i < 8; ++i) { x[i] = p[i * 64 + lane]; ss += x[i] * x[i]; }
  ss = wave_sum(ss);
  float d = fmaxf(sqrtf(ss), EPSN);
  float ee = 0.f;
#pragma unroll
  for (int i = 0; i < 8; ++i) { float y = x[i] / d; ee += y * y; }
  ee = wave_sum(ee);
  if (lane == 0) eepair[row] = make_float2(ee, 1.0f / d);
}

// one wave per z row: zinv[n] = 1/max(||z_n||,eps)  (used by finalize only)
__global__ __launch_bounds__(256) void z_norm_kernel(
    const float* __restrict__ z, float* __restrict__ zinv) {
  int row = blockIdx.x * 4 + (threadIdx.x >> 6);
  int lane = threadIdx.x & 63;
  const float* p = z + (size_t)row * DIM;
  float ss = 0.f;
#pragma unroll
  for (int i = 0; i < 8; ++i) { float v = p[i * 64 + lane]; ss += v * v; }
  ss = wave_sum(ss);
  if (lane == 0) zinv[row] = 1.0f / fmaxf(sqrtf(ss), EPSN);
}

// ---------------- emb -> swizzled hi/lo fp16 of (embn * 1024) --------------
// swz layout: chunk c = (tile16 * 16 + kc) * 2 + half, each chunk = 64 lanes
// x 8 f16 (1 KB); element (lane = quad*16+col, j) = embn[tile16*16+col]
// [kc*32 + quad*8 + j] * 1024, split hi/lo. Normalized codebook (x1024 keeps
// the lo half out of fp16 subnormals) makes argmin(dist) == argmax(dot):
// ||zn||^2 is per-row constant and ||embn||^2 = 1 +- 2^-23, perturbation
// ~100x below the fp16 hi/lo dot error that already passes.
__global__ __launch_bounds__(256) void emb_split_kernel(
    const float* __restrict__ emb, const float2* __restrict__ eepair,
    _Float16* __restrict__ swz) {
  int g = blockIdx.x * 256 + threadIdx.x;  // = t*1024 + kc*64 + lane
  int lane = g & 63;
  int kc = (g >> 6) & 15;
  int t = g >> 10;
  int code = t * 16 + (lane & 15);
  int k0 = kc * 32 + (lane >> 4) * 8;
  float sc = 1024.0f * eepair[code].y;
  const float* src = emb + (size_t)code * DIM + k0;
  float4 a = *(const float4*)src;
  float4 b = *(const float4*)(src + 4);
  float v[8] = {a.x, a.y, a.z, a.w, b.x, b.y, b.z, b.w};
  f16x8 h, l;
#pragma unroll
  for (int k = 0; k < 8; ++k) {
    float vs = v[k] * sc;
    _Float16 hh = (_Float16)vs;
    h[k] = hh;
    l[k] = (_Float16)(vs - (float)hh);
  }
  size_t cbase = ((size_t)(t * 16 + kc) * 2) * 512;  // f16 units
  *(f16x8*)&swz[cbase + lane * 8] = h;
  *(f16x8*)&swz[cbase + 512 + lane * 8] = l;
}

// ---------------- MFMA dot + per-partition argmax ----------------
// r5 (776us) validated: LDS-read roofline, 576KB/tile-pair @ ~81 B/cyc =
// 7270 cyc measured. r7 (32 rows/wave @ 1 wave/SIMD) regressed to 5650
// cyc/tile: no TLP -> all ds_read->MFMA latency exposed. Lesson: keep
// >=2 waves/SIMD; attack the LDS roofline by moving traffic to the IDLE
// vmem port instead. Split B by hi/lo: hi half staged in LDS exactly as r5
// (16KB/tile), lo half read DIRECTLY from global into registers (BL[16],
// statically indexed). The lo chunks are L2-resident (2.1MB partition) and
// shared by all 8 waves of a block -> L1-served. Read-only data, no sync
// interaction. Per tile-pair/CU: LDS 288KB/81 ~= 3555 cyc || vmem 256KB/~64
// ~= 4000 cyc || matrix 3725 cyc -> ~4000-4400 vs r5's 7270.
// Skeleton is byte-identical r5: 512 thr, 16 rows/wave, 2 waves/SIMD
// (launch_bounds(512,2)), plain __syncthreads() only (no inline-asm sync --
// r4's nondeterminism), 2-unrolled ping-pong, reg-staged hi (per-lane
// dwordx4 -> regs -> ds_write), partition (blockIdx&7) == XCD slice.
#define MFMA16(A, B, C) __builtin_amdgcn_mfma_f32_16x16x32_f16(A, B, C, 0, 0, 0)

__global__ __launch_bounds__(512, 2) void dist_argmin_kernel(
    const float* __restrict__ z, const _Float16* __restrict__ swz,
    int ne, int nrows, float* __restrict__ pscore, int* __restrict__ pidx) {
  __shared__ __attribute__((aligned(16))) _Float16 Bb[2][8192];  // 2 x 16 KB

  const int tid = threadIdx.x;
  const int wave = tid >> 6;   // 0..7
  const int lane = tid & 63;
  const int col = lane & 15;
  const int quad = lane >> 4;
  const int part = blockIdx.x & 7;          // codebook partition
  const int r0 = (blockIdx.x >> 3) * 128 + wave * 16;
  const int ntl = ne >> 7;                  // 64 16-code tiles per partition
  const int tbase = part * ntl;             // global tile base

  float best[4] = {-FLT_MAX, -FLT_MAX, -FLT_MAX, -FLT_MAX};
  int bidx[4] = {0, 0, 0, 0};

  // ---- hi staging: wave covers 2 hi-chunks (16KB tile / 8 waves) ----
  // hi chunk kc lives at global offset kc*1024 (even chunk slots).
  f16x8 R0[2], R1[2];
  auto load_tile = [&](int t, f16x8* R) {
    const _Float16* gb =
        swz + (size_t)(tbase + t) * 16384 + (size_t)(wave * 2) * 1024 +
        lane * 8;
#pragma unroll
    for (int i = 0; i < 2; ++i) R[i] = *(const f16x8*)(gb + i * 1024);
  };
  auto write_tile = [&](int buf, const f16x8* R) {
    _Float16* lb = &Bb[buf][(wave * 2) * 512 + lane * 8];
#pragma unroll
    for (int i = 0; i < 2; ++i) *(f16x8*)(lb + i * 512) = R[i];
  };

  // issue tiles 0,1 hi loads first; they complete under the A-fragment build
  load_tile(0, R0);
  load_tile(1, R1);

  // persistent A fragments (hi/lo) for this wave's 16 rows, from RAW z
  // (argmax of dot is invariant to the positive per-row scale zinv).
  // 128 VGPRs -- spill-free at 2 waves/SIMD (r5-verified).
  f16x8 Ah[16], Al[16];
  {
    const float* zp = z + (size_t)(r0 + col) * DIM + quad * 8;
#pragma unroll
    for (int kc = 0; kc < 16; ++kc) {
      float4 a = *(const float4*)(zp + kc * 32);
      float4 b = *(const float4*)(zp + kc * 32 + 4);
      float v[8] = {a.x, a.y, a.z, a.w, b.x, b.y, b.z, b.w};
#pragma unroll
      for (int k = 0; k < 8; ++k) {
        _Float16 h = (_Float16)v[k];
        Ah[kc][k] = h;
        Al[kc][k] = (_Float16)(v[k] - (float)h);
      }
    }
  }

  // lo chunks direct from global (L1/L2 path), single-buffered per tile;
  // lo chunk kc lives at global offset kc*1024 + 512 (odd chunk slots).
  f16x8 BL[16];
  auto preload_bl = [&](int t) {
    const _Float16* gb =
        swz + (size_t)(tbase + t) * 16384 + 512 + lane * 8;
#pragma unroll
    for (int kc = 0; kc < 16; ++kc)
      BL[kc] = *(const f16x8*)(gb + (size_t)kc * 1024);
  };

  auto compute_tile = [&](int t, int buf) {
    f32x4 a0 = (f32x4){0.f, 0.f, 0.f, 0.f};
    f32x4 a1 = a0, a2 = a0;
    const _Float16* bp = &Bb[buf][lane * 8];
    __builtin_amdgcn_s_setprio(1);
#pragma unroll
    for (int kc = 0; kc < 16; ++kc) {
      f16x8 bh = *(const f16x8*)(bp + kc * 512);
      a0 = MFMA16(Ah[kc], bh, a0);
      a1 = MFMA16(Al[kc], bh, a1);
      a2 = MFMA16(Ah[kc], BL[kc], a2);
    }
    __builtin_amdgcn_s_setprio(0);
    // pure argmax; tiles ascend in j within the partition, so strict '>'
    // keeps the first (lowest) index on ties.
    int j = (tbase + t) * 16 + col;
#pragma unroll
    for (int i = 0; i < 4; ++i) {
      float d = a0[i] + a1[i] + a2[i];
      if (d > best[i]) { best[i] = d; bidx[i] = j; }
    }
  };

  // prologue: buf0 <- tile0 hi (compiler inserts the counted vmcnt for R0)
  write_tile(0, R0);
  __syncthreads();

  // 2-unrolled ping-pong, one __syncthreads per tile (r5-verified skeleton).
  // Buffer safety: the write to buf X is after compute(buf X)'s reads
  // drained at the previous barrier, and before the barrier that precedes
  // the next compute(buf X). Register safety: load overwrites R[x] only
  // after R[x]'s ds_writes issued (DS reads operands at issue) behind a
  // barrier. BL is read-only global data consumed in the same tile --
  // no cross-wave hazard, no sync interaction.
  for (int t = 0; t < ntl; t += 2) {          // ntl = 64, even
    if (t + 2 < ntl) load_tile(t + 2, R0);    // hi prefetch, hides
    preload_bl(t);                            // lo for THIS tile
    compute_tile(t, 0);
    write_tile(1, R1);                        // tile t+1 hi -> buf1
    __syncthreads();

    if (t + 3 < ntl) load_tile(t + 3, R1);
    preload_bl(t + 1);
    compute_tile(t + 1, 1);
    if (t + 2 < ntl) write_tile(0, R0);       // tile t+2 hi -> buf0
    __syncthreads();
  }

  // merge across the 16 columns within each quad (xor 1,2,4,8 stays in quad)
#pragma unroll
  for (int i = 0; i < 4; ++i) {
    float bs = best[i];
    int bj = bidx[i];
#pragma unroll
    for (int offm = 1; offm < 16; offm <<= 1) {
      float os = __shfl_xor(bs, offm, 64);
      int oi = __shfl_xor(bj, offm, 64);
      if (os > bs || (os == bs && oi < bj)) { bs = os; bj = oi; }
    }
    if (col == 0) {
      int row = r0 + quad * 4 + i;
      pscore[(size_t)part * nrows + row] = bs;
      pidx[(size_t)part * nrows + row] = bj;
    }
  }
}

// fold the 8 per-partition partials per row; ascending p + strict '>'
// preserves global first-index semantics (partitions hold ascending ranges)
__global__ __launch_bounds__(256) void merge_kernel(
    const float* __restrict__ pscore, const int* __restrict__ pidx,
    int nrows, int* __restrict__ idxw, float* __restrict__ counts,
    float* __restrict__ out_idx) {
  int row = blockIdx.x * 256 + threadIdx.x;
  float bs = pscore[row];
  int bj = pidx[row];
#pragma unroll
  for (int p = 1; p < 8; ++p) {
    float s = pscore[(size_t)p * nrows + row];
    int j2 = pidx[(size_t)p * nrows + row];
    if (s > bs || (s == bs && j2 < bj)) { bs = s; bj = j2; }
  }
  idxw[row] = bj;
  out_idx[row] = (float)bj;
  atomicAdd(&counts[bj], 1.0f);
}

// one wave per row: z_q_st = normalize(q); per-block loss partial
__global__ __launch_bounds__(256) void finalize_rows_kernel(
    const float* __restrict__ z, const float* __restrict__ emb,
    const int* __restrict__ idxw, const float* __restrict__ zinv,
    float* __restrict__ out_zq, float* __restrict__ lpart) {
  __shared__ float red[4];
  int row = blockIdx.x * 4 + (threadIdx.x >> 6);
  int lane = threadIdx.x & 63;
  int j = idxw[row];
  const float* zp = z + (size_t)row * DIM;
  const float* qp = emb + (size_t)j * DIM;
  float zl[8], ql[8], tl[8];
  float st = 0.f, sq = 0.f;
#pragma unroll
  for (int i = 0; i < 8; ++i) {
    int k = i * 64 + lane;
    float zv = zp[k], qv = qp[k];
    float t = zv + (qv - zv);  // straight-through, literal arithmetic
    zl[i] = zv; ql[i] = qv; tl[i] = t;
    st += t * t;
    sq += qv * qv;
  }
  st = wave_sum(st);
  sq = wave_sum(sq);
  float dt = fmaxf(sqrtf(st), EPSN);
  float dq = fmaxf(sqrtf(sq), EPSN);
  float zi = zinv[row];
  float lp = 0.f;
#pragma unroll
  for (int i = 0; i < 8; ++i) {
    int k = i * 64 + lane;
    out_zq[(size_t)row * DIM + k] = tl[i] / dt;
    float e = ql[i] / dq - zl[i] * zi;
    lp += e * e;
  }
  lp = wave_sum(lp);
  if (lane == 0) red[threadIdx.x >> 6] = lp;
  __syncthreads();
  if (threadIdx.x == 0) lpart[blockIdx.x] = red[0] + red[1] + red[2] + red[3];
}

// single block: loss scalar (sum of block partials) + perplexity from counts
__global__ __launch_bounds__(256) void scalars_kernel(
    const float* __restrict__ counts, const float* __restrict__ lpart,
    int ne, int nblk, float inv_n, float inv_total,
    float* __restrict__ out_loss, float* __restrict__ out_perp) {
  __shared__ float red[8];
  int tid = threadIdx.x;
  float s = 0.f;
  for (int jj = tid; jj < ne; jj += 256) {
    float p = counts[jj] * inv_n;
    s += p * logf(p + 1e-10f);
  }
  float l = 0.f;
  for (int jj = tid; jj < nblk; jj += 256) l += lpart[jj];
  s = wave_sum(s);
  l = wave_sum(l);
  if ((tid & 63) == 0) { red[tid >> 6] = s; red[4 + (tid >> 6)] = l; }
  __syncthreads();
  if (tid == 0) {
    float t = red[0] + red[1] + red[2] + red[3];
    float lt = red[4] + red[5] + red[6] + red[7];
    *out_perp = expf(-t);
    *out_loss = 1.25f * lt * inv_total;  // (1+BETA)*mean, sg() identity fwd
  }
}

extern "C" void kernel_launch(void* const* d_in, const int* in_sizes, int n_in,
                              void* d_out, int out_size, void* d_ws, size_t ws_size,
                              hipStream_t stream) {
  const float* z = (const float*)d_in[0];
  const float* emb = (const float*)d_in[1];
  float* out = (float*)d_out;
  float* ws = (float*)d_ws;

  const int nrows = in_sizes[0] / DIM;  // 32768
  const int ne = in_sizes[1] / DIM;     // 8192
  const int nfin = nrows / 4;           // finalize blocks

  // workspace layout (floats)
  float2* eepair = (float2*)ws;                  // ne float2
  float* zinv = ws + 2 * ne;                     // nrows
  int* idxw = (int*)(ws + 2 * ne + nrows);       // nrows
  float* counts = ws + 2 * ne + 2 * nrows;       // ne
  float* lpart = counts + ne;                    // nfin
  float* pscore = lpart + nfin;                  // 8 * nrows
  int* pidx = (int*)(pscore + 8 * (size_t)nrows);// 8 * nrows
  _Float16* swz = (_Float16*)(pidx + 8 * (size_t)nrows);  // ne*1024 f16

  float* out_zq = out + 1;
  float* out_idx = out + 1 + (size_t)nrows * DIM;
  float* out_perp = out + (size_t)out_size - 1;

  hipMemsetAsync(counts, 0, ne * sizeof(float), stream);
  emb_norm_kernel<<<ne / 4, 256, 0, stream>>>(emb, eepair);
  z_norm_kernel<<<nrows / 4, 256, 0, stream>>>(z, zinv);
  emb_split_kernel<<<ne * 64 / 256, 256, 0, stream>>>(emb, eepair, swz);
  dist_argmin_kernel<<<(nrows / 128) * 8, 512, 0, stream>>>(z, swz, ne, nrows,
                                                            pscore, pidx);
  merge_kernel<<<nrows / 256, 256, 0, stream>>>(pscore, pidx, nrows,
                                                idxw, counts, out_idx);
  finalize_rows_kernel<<<nfin, 256, 0, stream>>>(z, emb, idxw, zinv,
                                                 out_zq, lpart);
  scalars_kernel<<<1, 256, 0, stream>>>(counts, lpart, ne, nfin,
                                        1.0f / (float)nrows,
                                        1.0f / (float)((size_t)nrows * DIM),
                                        out, out_perp);
}